// Round 2
// baseline (455.127 us; speedup 1.0000x reference)
//
#include <hip/hip_runtime.h>
#include <cstdint>
#include <cstddef>

#define RANK 16
#define NR   4   // rows per wave in the fused kernel

// ---------------------------------------------------------------------------
// Kernel 1: mix LoRA factors with per-(batch,split) skill weights.
//   At[b][r][k] = sum_s w[b][q][s] * la[q][s][d][r],   k = q*512 + d   (TRANSPOSED)
//   Bm[b][r][o] = 2 * sum_s w[b][q][s] * lb[q][s][r][dd], o = q*512 + dd
// (scaling = lora_alpha/rank = 2, folded into Bm)
// ---------------------------------------------------------------------------
__global__ __launch_bounds__(256) void skilled_lora_mix(
    const float* __restrict__ w,   // [8][4][8]
    const float* __restrict__ la,  // [4][8][512][16]
    const float* __restrict__ lb,  // [4][8][16][512]
    float* __restrict__ At,        // [8][16][2048]  (k-major)
    float* __restrict__ Bm)        // [8][16][2048]  (o-major), pre-scaled by 2
{
  const int j = blockIdx.x * 256 + threadIdx.x;   // one float4 of output per thread
  if (j < 65536) {
    // ---- At: j -> (b, r, k4) ----
    const int k = (j & 511) * 4;          // 0..2044
    const int r = (j >> 9) & 15;
    const int b = j >> 13;
    const int q = k >> 9;
    const int d = k & 511;
    const float* wb = w + (b * 4 + q) * 8;
    float4 acc = make_float4(0.f, 0.f, 0.f, 0.f);
#pragma unroll
    for (int s = 0; s < 8; ++s) {
      const float ws = wb[s];
      const float* lap = la + (size_t)(((q * 8 + s) * 512 + d) * 16 + r);
      acc.x = fmaf(ws, lap[0],  acc.x);   // la[q][s][d+0][r]
      acc.y = fmaf(ws, lap[16], acc.y);   // la[q][s][d+1][r]
      acc.z = fmaf(ws, lap[32], acc.z);
      acc.w = fmaf(ws, lap[48], acc.w);
    }
    *reinterpret_cast<float4*>(At + (size_t)((b * 16 + r) * 2048 + k)) = acc;
  } else {
    // ---- Bm: jj -> (b, r, o4) ----
    const int jj = j - 65536;
    const int o  = (jj & 511) * 4;
    const int r  = (jj >> 9) & 15;
    const int b  = jj >> 13;
    const int q  = o >> 9;
    const int dd = o & 511;
    const float* wb = w + (b * 4 + q) * 8;
    float4 acc = make_float4(0.f, 0.f, 0.f, 0.f);
#pragma unroll
    for (int s = 0; s < 8; ++s) {
      const float ws = wb[s];
      const float4 v = *reinterpret_cast<const float4*>(
          lb + (size_t)(((q * 8 + s) * 16 + r) * 512 + dd));
      acc.x = fmaf(ws, v.x, acc.x);
      acc.y = fmaf(ws, v.y, acc.y);
      acc.z = fmaf(ws, v.z, acc.z);
      acc.w = fmaf(ws, v.w, acc.w);
    }
    acc.x *= 2.f; acc.y *= 2.f; acc.z *= 2.f; acc.w *= 2.f;
    *reinterpret_cast<float4*>(Bm + (size_t)((b * 16 + r) * 2048 + o)) = acc;
  }
}

// ---------------------------------------------------------------------------
// Kernel 2: fused  tmp = input @ A ;  out = tmp @ B   — no input LDS staging.
//
// Wave-parallel decomposition: each wave owns NR=4 full rows end-to-end.
// Lane = (r = lane&15, ks = lane>>4). Phase 1 K-loop, window of 16 k:
//   a4 = At[b][r][k0 + ks*4 .. +3]          (per-lane float4, L2-hot)
//   x4 = in[row_i][k0 + ks*4 .. +3]         (16-lane-redundant -> 64B/wave fetch)
//   acc_i += dot(x4, a4)                    (4 FMA x NR rows per window)
// Reduce over ks via 2x shfl_xor; tmp (4x16 floats) parked in 2KB LDS;
// Phase 2 reads tmp as uniform-address b128 broadcasts, B in 16 float4 regs
// per 256-column strip, coalesced float4 stores. No __syncthreads anywhere.
// ---------------------------------------------------------------------------
__global__ __launch_bounds__(512, 4) void skilled_lora_fused(
    const float* __restrict__ input,   // [8][2048][2048]
    const float* __restrict__ At,      // [8][16][2048]
    const float* __restrict__ Bm,      // [8][16][2048] (pre-scaled by 2)
    float* __restrict__ out)           // [8][2048][2048]
{
  __shared__ float tmpw[8 * NR * RANK];              // 2 KB, wave-private slices

  const int tid  = threadIdx.x;
  const int lane = tid & 63;
  const int wv   = tid >> 6;                         // 0..7
  const int gw   = blockIdx.x * 8 + wv;              // global wave id, 0..4095
  const int row0 = gw * NR;                          // first of this wave's 4 rows
  const int b    = row0 >> 11;                       // batch (uniform per wave)
  const int r    = lane & 15;
  const int ks   = lane >> 4;

  // ---------------- phase 1: acc_i = <input[row_i], At[r]> over k ≡ ks ------
  const float* Atr = At + (size_t)(b * 16 + r) * 2048 + ks * 4;
  const float* x0  = input + (size_t)row0 * 2048 + ks * 4;

  float acc0 = 0.f, acc1 = 0.f, acc2 = 0.f, acc3 = 0.f;
#pragma unroll 2
  for (int k0 = 0; k0 < 2048; k0 += 16) {
    const float4 a4 = *reinterpret_cast<const float4*>(Atr + k0);
    const float4 xa = *reinterpret_cast<const float4*>(x0 + k0);
    const float4 xb = *reinterpret_cast<const float4*>(x0 + 2048 + k0);
    const float4 xc = *reinterpret_cast<const float4*>(x0 + 4096 + k0);
    const float4 xd = *reinterpret_cast<const float4*>(x0 + 6144 + k0);
    acc0 = fmaf(xa.x, a4.x, acc0); acc0 = fmaf(xa.y, a4.y, acc0);
    acc0 = fmaf(xa.z, a4.z, acc0); acc0 = fmaf(xa.w, a4.w, acc0);
    acc1 = fmaf(xb.x, a4.x, acc1); acc1 = fmaf(xb.y, a4.y, acc1);
    acc1 = fmaf(xb.z, a4.z, acc1); acc1 = fmaf(xb.w, a4.w, acc1);
    acc2 = fmaf(xc.x, a4.x, acc2); acc2 = fmaf(xc.y, a4.y, acc2);
    acc2 = fmaf(xc.z, a4.z, acc2); acc2 = fmaf(xc.w, a4.w, acc2);
    acc3 = fmaf(xd.x, a4.x, acc3); acc3 = fmaf(xd.y, a4.y, acc3);
    acc3 = fmaf(xd.z, a4.z, acc3); acc3 = fmaf(xd.w, a4.w, acc3);
  }

  // reduce the 4 ks-slices (lanes r, r+16, r+32, r+48) -> full dot product
  acc0 += __shfl_xor(acc0, 16); acc0 += __shfl_xor(acc0, 32);
  acc1 += __shfl_xor(acc1, 16); acc1 += __shfl_xor(acc1, 32);
  acc2 += __shfl_xor(acc2, 16); acc2 += __shfl_xor(acc2, 32);
  acc3 += __shfl_xor(acc3, 16); acc3 += __shfl_xor(acc3, 32);

  float* tp = tmpw + wv * (NR * RANK);
  if (ks == 0) {                       // lanes 0..15 hold r = lane
    tp[0 * RANK + r] = acc0;
    tp[1 * RANK + r] = acc1;
    tp[2 * RANK + r] = acc2;
    tp[3 * RANK + r] = acc3;
  }
  // same-wave ds_write -> ds_read: compiler inserts lgkmcnt; no barrier needed.

  // ---------------- phase 2: out[row_i][:] = tmp[i][:] @ B ------------------
  const float* Bb  = Bm + (size_t)b * (RANK * 2048);
  float* op = out + (size_t)row0 * 2048 + lane * 4;

  for (int s = 0; s < 8; ++s) {
    const int oc = s * 256;
    float4 B4[RANK];
#pragma unroll
    for (int rr = 0; rr < RANK; ++rr)
      B4[rr] = *reinterpret_cast<const float4*>(Bb + (size_t)rr * 2048 + oc + lane * 4);
#pragma unroll
    for (int i = 0; i < NR; ++i) {
      const float4 t0 = *reinterpret_cast<const float4*>(tp + i * RANK);      // uniform
      const float4 t1 = *reinterpret_cast<const float4*>(tp + i * RANK + 4);  // addr ->
      const float4 t2 = *reinterpret_cast<const float4*>(tp + i * RANK + 8);  // LDS
      const float4 t3 = *reinterpret_cast<const float4*>(tp + i * RANK + 12); // broadcast
      float4 a = make_float4(0.f, 0.f, 0.f, 0.f);
      const float tv[RANK] = {t0.x, t0.y, t0.z, t0.w, t1.x, t1.y, t1.z, t1.w,
                              t2.x, t2.y, t2.z, t2.w, t3.x, t3.y, t3.z, t3.w};
#pragma unroll
      for (int rr = 0; rr < RANK; ++rr) {
        a.x = fmaf(tv[rr], B4[rr].x, a.x);
        a.y = fmaf(tv[rr], B4[rr].y, a.y);
        a.z = fmaf(tv[rr], B4[rr].z, a.z);
        a.w = fmaf(tv[rr], B4[rr].w, a.w);
      }
      *reinterpret_cast<float4*>(op + (size_t)i * 2048 + oc) = a;
    }
  }
}

// ---------------------------------------------------------------------------
extern "C" void kernel_launch(void* const* d_in, const int* in_sizes, int n_in,
                              void* d_out, int out_size, void* d_ws, size_t ws_size,
                              hipStream_t stream) {
  const float* input = (const float*)d_in[0];   // [8][2048][2048]
  const float* w     = (const float*)d_in[1];   // [8][4][8]
  const float* la    = (const float*)d_in[2];   // [4][8][512][16]
  const float* lb    = (const float*)d_in[3];   // [4][8][16][512]
  float* outp = (float*)d_out;

  float* At = (float*)d_ws;                     // 262144 floats (1 MB)
  float* Bm = At + 8 * 16 * 2048;               // 262144 floats (1 MB)

  skilled_lora_mix<<<512, 256, 0, stream>>>(w, la, lb, At, Bm);
  skilled_lora_fused<<<512, 512, 0, stream>>>(input, At, Bm, outp);
}

// Round 4
// 202.093 us; speedup vs baseline: 2.2521x; 2.2521x over previous
//
#include <hip/hip_runtime.h>
#include <cstdint>
#include <cstddef>

#define RANK 16

// ---------------------------------------------------------------------------
// Kernel 1: mix LoRA factors with per-(batch,split) skill weights.
//   At[b][r][k] = sum_s w[b][q][s] * la[q][s][d][r],   k = q*512 + d  (k-major)
//   Bm[b][r][o] = 2 * sum_s w[b][q][s] * lb[q][s][r][dd], o = q*512 + dd
// (scaling = lora_alpha/rank = 2, folded into Bm)
// ---------------------------------------------------------------------------
__global__ __launch_bounds__(256) void skilled_lora_mix(
    const float* __restrict__ w,   // [8][4][8]
    const float* __restrict__ la,  // [4][8][512][16]
    const float* __restrict__ lb,  // [4][8][16][512]
    float* __restrict__ At,        // [8][16][2048]
    float* __restrict__ Bm)        // [8][16][2048], pre-scaled by 2
{
  const int j = blockIdx.x * 256 + threadIdx.x;
  if (j < 65536) {
    const int k = (j & 511) * 4;
    const int r = (j >> 9) & 15;
    const int b = j >> 13;
    const int q = k >> 9;
    const int d = k & 511;
    const float* wb = w + (b * 4 + q) * 8;
    float4 acc = make_float4(0.f, 0.f, 0.f, 0.f);
#pragma unroll
    for (int s = 0; s < 8; ++s) {
      const float ws = wb[s];
      const float* lap = la + (size_t)(((q * 8 + s) * 512 + d) * 16 + r);
      acc.x = fmaf(ws, lap[0],  acc.x);
      acc.y = fmaf(ws, lap[16], acc.y);
      acc.z = fmaf(ws, lap[32], acc.z);
      acc.w = fmaf(ws, lap[48], acc.w);
    }
    *reinterpret_cast<float4*>(At + (size_t)((b * 16 + r) * 2048 + k)) = acc;
  } else {
    const int jj = j - 65536;
    const int o  = (jj & 511) * 4;
    const int r  = (jj >> 9) & 15;
    const int b  = jj >> 13;
    const int q  = o >> 9;
    const int dd = o & 511;
    const float* wb = w + (b * 4 + q) * 8;
    float4 acc = make_float4(0.f, 0.f, 0.f, 0.f);
#pragma unroll
    for (int s = 0; s < 8; ++s) {
      const float ws = wb[s];
      const float4 v = *reinterpret_cast<const float4*>(
          lb + (size_t)(((q * 8 + s) * 16 + r) * 512 + dd));
      acc.x = fmaf(ws, v.x, acc.x);
      acc.y = fmaf(ws, v.y, acc.y);
      acc.z = fmaf(ws, v.z, acc.z);
      acc.w = fmaf(ws, v.w, acc.w);
    }
    acc.x *= 2.f; acc.y *= 2.f; acc.z *= 2.f; acc.w *= 2.f;
    *reinterpret_cast<float4*>(Bm + (size_t)((b * 16 + r) * 2048 + o)) = acc;
  }
}

// ---------------------------------------------------------------------------
// Kernel 2 (phase A): tmp[b][row][r] = sum_k X[b][row][k] * A[b][k][r]
// Block: 256 thr = 4 waves, 32 rows. Wave w owns k-window [w*512, w*512+512).
// Per 64-k chunk: stage X (32 rows x 64k, stride-65) + At tile (64k x 16r)
// into wave-private LDS; compute with lane=(row32, h=k-half):
//   per kk: 1 ds_read_b32 (x) + 4 broadcast ds_read_b128 (At row) + 16 FMA.
// No s_loads, no barriers in the hot loop. One __syncthreads for the final
// 8-way (4 waves x 2 halves) cross-wave reduction.
// ---------------------------------------------------------------------------
#define ROWS_A 32
#define KWIN   512
#define KCH    64

__global__ __launch_bounds__(256, 2) void lora_phase_a(
    const float* __restrict__ X,    // [8][2048][2048]
    const float* __restrict__ At,   // [8][16][2048] (k-major per r)
    float* __restrict__ tmp)        // [8][2048][16]
{
  __shared__ float bufX[4][ROWS_A][65];                 // 33.3 KB
  __shared__ __align__(16) float bufA[4][KCH][RANK];    // 16 KB
  __shared__ __align__(16) float part[8][ROWS_A][RANK]; // 16 KB

  const int tid   = threadIdx.x;
  const int lane  = tid & 63;
  const int wv    = tid >> 6;            // 0..3
  const int b     = blockIdx.x >> 6;     // 8 batches x 64 row-tiles
  const int rt    = blockIdx.x & 63;
  const int row0  = rt * ROWS_A;
  const int kw    = wv * KWIN;

  const int row32 = lane & 31;
  const int h     = lane >> 5;           // k-half within chunk
  const int rA    = lane & 15;           // for At staging
  const int k16   = lane >> 4;

  const float* Xb = X + ((size_t)(b * 2048 + row0)) * 2048;
  const float* Ab = At + (size_t)b * (RANK * 2048);

  float acc[RANK];
#pragma unroll
  for (int r = 0; r < RANK; ++r) acc[r] = 0.f;

  for (int c = 0; c < KWIN / KCH; ++c) {   // 8 chunks
    const int kbase = kw + c * KCH;

    // ---- stage X: 32 rows x 64 k (256B coalesced per instr) ----
#pragma unroll 8
    for (int rr = 0; rr < ROWS_A; ++rr)
      bufX[wv][rr][lane] = Xb[(size_t)rr * 2048 + kbase + lane];

    // ---- stage At tile: 64k x 16r, from k-major At[b][r][k] ----
#pragma unroll
    for (int i = 0; i < 4; ++i) {
      const float4 v = *reinterpret_cast<const float4*>(
          Ab + (size_t)rA * 2048 + kbase + i * 16 + k16 * 4);
      bufA[wv][i * 16 + k16 * 4 + 0][rA] = v.x;
      bufA[wv][i * 16 + k16 * 4 + 1][rA] = v.y;
      bufA[wv][i * 16 + k16 * 4 + 2][rA] = v.z;
      bufA[wv][i * 16 + k16 * 4 + 3][rA] = v.w;
    }
    // wave-private buffers: same-wave DS ops are in-order; no barrier needed.

    // ---- compute: 32 kk (this lane's k-half) x 16 r ----
    const float* xr = &bufX[wv][row32][h * 32];
    const float* ar = &bufA[wv][h * 32][0];
#pragma unroll 4
    for (int kk = 0; kk < 32; ++kk) {
      const float x = xr[kk];
      const float4 a0 = *reinterpret_cast<const float4*>(ar + kk * RANK);
      const float4 a1 = *reinterpret_cast<const float4*>(ar + kk * RANK + 4);
      const float4 a2 = *reinterpret_cast<const float4*>(ar + kk * RANK + 8);
      const float4 a3 = *reinterpret_cast<const float4*>(ar + kk * RANK + 12);
      acc[0]  = fmaf(x, a0.x, acc[0]);  acc[1]  = fmaf(x, a0.y, acc[1]);
      acc[2]  = fmaf(x, a0.z, acc[2]);  acc[3]  = fmaf(x, a0.w, acc[3]);
      acc[4]  = fmaf(x, a1.x, acc[4]);  acc[5]  = fmaf(x, a1.y, acc[5]);
      acc[6]  = fmaf(x, a1.z, acc[6]);  acc[7]  = fmaf(x, a1.w, acc[7]);
      acc[8]  = fmaf(x, a2.x, acc[8]);  acc[9]  = fmaf(x, a2.y, acc[9]);
      acc[10] = fmaf(x, a2.z, acc[10]); acc[11] = fmaf(x, a2.w, acc[11]);
      acc[12] = fmaf(x, a3.x, acc[12]); acc[13] = fmaf(x, a3.y, acc[13]);
      acc[14] = fmaf(x, a3.z, acc[14]); acc[15] = fmaf(x, a3.w, acc[15]);
    }
  }

  // ---- park per-(wave,half) partials, then 8-way reduce ----
  float* pp = &part[wv * 2 + h][row32][0];
#pragma unroll
  for (int rq = 0; rq < 4; ++rq)
    *reinterpret_cast<float4*>(pp + rq * 4) =
        make_float4(acc[rq * 4], acc[rq * 4 + 1], acc[rq * 4 + 2], acc[rq * 4 + 3]);
  __syncthreads();

  // FIX (round-3 bug): 512 (row, r) pairs but 256 threads -> 2-iteration
  // grid-stride loop. Previous code covered only rows 0..15, leaving rows
  // 16..31 of tmp unwritten (0xAA poison -> half the output was ~0).
#pragma unroll
  for (int v = tid; v < ROWS_A * RANK; v += 256) {
    const int row = v >> 4;        // 0..31
    const int r   = v & 15;
    float s = 0.f;
#pragma unroll
    for (int p = 0; p < 8; ++p) s += part[p][row][r];
    tmp[((size_t)(b * 2048 + row0 + row)) * RANK + r] = s;
  }
}

// ---------------------------------------------------------------------------
// Kernel 3 (phase B): out[b][row][o] = sum_r tmp[b][row][r] * Bm[b][r][o]
// Block: 256 thr, 1024-col strip (thread = 4 cols, B-slab in 64 VGPRs),
// 64 rows. tmp rows are block-uniform -> scalar loads, prefetched by unroll.
// Pure streaming-write kernel, no LDS.
// ---------------------------------------------------------------------------
__global__ __launch_bounds__(256, 4) void lora_phase_b(
    const float* __restrict__ tmp,  // [8][2048][16]
    const float* __restrict__ Bm,   // [8][16][2048] (pre-scaled by 2)
    float* __restrict__ out)        // [8][2048][2048]
{
  const int tid  = threadIdx.x;
  const int b    = blockIdx.x >> 6;          // 8 batches
  const int oh   = (blockIdx.x >> 5) & 1;    // column half
  const int rt   = blockIdx.x & 31;          // row tile
  const int row0 = rt * 64;
  const int o0   = oh * 1024 + tid * 4;

  const float* Bb = Bm + (size_t)b * (RANK * 2048) + o0;
  float4 B4[RANK];
#pragma unroll
  for (int r = 0; r < RANK; ++r)
    B4[r] = *reinterpret_cast<const float4*>(Bb + (size_t)r * 2048);

  const float* tp = tmp + ((size_t)(b * 2048 + row0)) * RANK;
  float* op = out + ((size_t)(b * 2048 + row0)) * 2048 + o0;

#pragma unroll 4
  for (int rr = 0; rr < 64; ++rr) {
    const float4 t0 = *reinterpret_cast<const float4*>(tp + rr * RANK);
    const float4 t1 = *reinterpret_cast<const float4*>(tp + rr * RANK + 4);
    const float4 t2 = *reinterpret_cast<const float4*>(tp + rr * RANK + 8);
    const float4 t3 = *reinterpret_cast<const float4*>(tp + rr * RANK + 12);
    const float tv[RANK] = {t0.x, t0.y, t0.z, t0.w, t1.x, t1.y, t1.z, t1.w,
                            t2.x, t2.y, t2.z, t2.w, t3.x, t3.y, t3.z, t3.w};
    float4 a = make_float4(0.f, 0.f, 0.f, 0.f);
#pragma unroll
    for (int r = 0; r < RANK; ++r) {
      a.x = fmaf(tv[r], B4[r].x, a.x);
      a.y = fmaf(tv[r], B4[r].y, a.y);
      a.z = fmaf(tv[r], B4[r].z, a.z);
      a.w = fmaf(tv[r], B4[r].w, a.w);
    }
    *reinterpret_cast<float4*>(op + (size_t)rr * 2048) = a;
  }
}

// ---------------------------------------------------------------------------
extern "C" void kernel_launch(void* const* d_in, const int* in_sizes, int n_in,
                              void* d_out, int out_size, void* d_ws, size_t ws_size,
                              hipStream_t stream) {
  const float* input = (const float*)d_in[0];   // [8][2048][2048]
  const float* w     = (const float*)d_in[1];   // [8][4][8]
  const float* la    = (const float*)d_in[2];   // [4][8][512][16]
  const float* lb    = (const float*)d_in[3];   // [4][8][16][512]
  float* outp = (float*)d_out;

  float* At  = (float*)d_ws;                    // 262144 floats (1 MB)
  float* Bm  = At + 8 * RANK * 2048;            // 262144 floats (1 MB)
  float* tmp = Bm + 8 * RANK * 2048;            // 262144 floats (1 MB)

  skilled_lora_mix<<<512, 256, 0, stream>>>(w, la, lb, At, Bm);
  lora_phase_a<<<512, 256, 0, stream>>>(input, At, tmp);
  lora_phase_b<<<512, 256, 0, stream>>>(tmp, Bm, outp);
}

// Round 5
// 96.033 us; speedup vs baseline: 4.7393x; 2.1044x over previous
//
#include <hip/hip_runtime.h>
#include <cstdint>
#include <cstddef>

#define RANK 16

// ---------------------------------------------------------------------------
// Kernel 1: mix LoRA factors with per-(batch,split) skill weights.
//   At[b][r][k] = sum_s w[b][q][s] * la[q][s][d][r],   k = q*512 + d  (k-major)
//   Bm[b][r][o] = 2 * sum_s w[b][q][s] * lb[q][s][r][dd], o = q*512 + dd
// (scaling = lora_alpha/rank = 2, folded into Bm)
// ---------------------------------------------------------------------------
__global__ __launch_bounds__(256) void skilled_lora_mix(
    const float* __restrict__ w,   // [8][4][8]
    const float* __restrict__ la,  // [4][8][512][16]
    const float* __restrict__ lb,  // [4][8][16][512]
    float* __restrict__ At,        // [8][16][2048]
    float* __restrict__ Bm)        // [8][16][2048], pre-scaled by 2
{
  const int j = blockIdx.x * 256 + threadIdx.x;
  if (j < 65536) {
    const int k = (j & 511) * 4;
    const int r = (j >> 9) & 15;
    const int b = j >> 13;
    const int q = k >> 9;
    const int d = k & 511;
    const float* wb = w + (b * 4 + q) * 8;
    float4 acc = make_float4(0.f, 0.f, 0.f, 0.f);
#pragma unroll
    for (int s = 0; s < 8; ++s) {
      const float ws = wb[s];
      const float* lap = la + (size_t)(((q * 8 + s) * 512 + d) * 16 + r);
      acc.x = fmaf(ws, lap[0],  acc.x);
      acc.y = fmaf(ws, lap[16], acc.y);
      acc.z = fmaf(ws, lap[32], acc.z);
      acc.w = fmaf(ws, lap[48], acc.w);
    }
    *reinterpret_cast<float4*>(At + (size_t)((b * 16 + r) * 2048 + k)) = acc;
  } else {
    const int jj = j - 65536;
    const int o  = (jj & 511) * 4;
    const int r  = (jj >> 9) & 15;
    const int b  = jj >> 13;
    const int q  = o >> 9;
    const int dd = o & 511;
    const float* wb = w + (b * 4 + q) * 8;
    float4 acc = make_float4(0.f, 0.f, 0.f, 0.f);
#pragma unroll
    for (int s = 0; s < 8; ++s) {
      const float ws = wb[s];
      const float4 v = *reinterpret_cast<const float4*>(
          lb + (size_t)(((q * 8 + s) * 16 + r) * 512 + dd));
      acc.x = fmaf(ws, v.x, acc.x);
      acc.y = fmaf(ws, v.y, acc.y);
      acc.z = fmaf(ws, v.z, acc.z);
      acc.w = fmaf(ws, v.w, acc.w);
    }
    acc.x *= 2.f; acc.y *= 2.f; acc.z *= 2.f; acc.w *= 2.f;
    *reinterpret_cast<float4*>(Bm + (size_t)((b * 16 + r) * 2048 + o)) = acc;
  }
}

// ---------------------------------------------------------------------------
// Kernel 2 (phase A): tmp[b][row][r] = sum_k X[b][row][k] * A[b][k][r]
// (unchanged from round 4 — ~38 µs, to be revisited once phase B is fixed)
// ---------------------------------------------------------------------------
#define ROWS_A 32
#define KWIN   512
#define KCH    64

__global__ __launch_bounds__(256, 2) void lora_phase_a(
    const float* __restrict__ X,    // [8][2048][2048]
    const float* __restrict__ At,   // [8][16][2048] (k-major per r)
    float* __restrict__ tmp)        // [8][2048][16]
{
  __shared__ float bufX[4][ROWS_A][65];                 // 33.3 KB
  __shared__ __align__(16) float bufA[4][KCH][RANK];    // 16 KB
  __shared__ __align__(16) float part[8][ROWS_A][RANK]; // 16 KB

  const int tid   = threadIdx.x;
  const int lane  = tid & 63;
  const int wv    = tid >> 6;            // 0..3
  const int b     = blockIdx.x >> 6;     // 8 batches x 64 row-tiles
  const int rt    = blockIdx.x & 63;
  const int row0  = rt * ROWS_A;
  const int kw    = wv * KWIN;

  const int row32 = lane & 31;
  const int h     = lane >> 5;           // k-half within chunk
  const int rA    = lane & 15;           // for At staging
  const int k16   = lane >> 4;

  const float* Xb = X + ((size_t)(b * 2048 + row0)) * 2048;
  const float* Ab = At + (size_t)b * (RANK * 2048);

  float acc[RANK];
#pragma unroll
  for (int r = 0; r < RANK; ++r) acc[r] = 0.f;

  for (int c = 0; c < KWIN / KCH; ++c) {   // 8 chunks
    const int kbase = kw + c * KCH;

    // ---- stage X: 32 rows x 64 k (256B coalesced per instr) ----
#pragma unroll 8
    for (int rr = 0; rr < ROWS_A; ++rr)
      bufX[wv][rr][lane] = Xb[(size_t)rr * 2048 + kbase + lane];

    // ---- stage At tile: 64k x 16r, from k-major At[b][r][k] ----
#pragma unroll
    for (int i = 0; i < 4; ++i) {
      const float4 v = *reinterpret_cast<const float4*>(
          Ab + (size_t)rA * 2048 + kbase + i * 16 + k16 * 4);
      bufA[wv][i * 16 + k16 * 4 + 0][rA] = v.x;
      bufA[wv][i * 16 + k16 * 4 + 1][rA] = v.y;
      bufA[wv][i * 16 + k16 * 4 + 2][rA] = v.z;
      bufA[wv][i * 16 + k16 * 4 + 3][rA] = v.w;
    }
    // wave-private buffers: same-wave DS ops are in-order; no barrier needed.

    // ---- compute: 32 kk (this lane's k-half) x 16 r ----
    const float* xr = &bufX[wv][row32][h * 32];
    const float* ar = &bufA[wv][h * 32][0];
#pragma unroll 4
    for (int kk = 0; kk < 32; ++kk) {
      const float x = xr[kk];
      const float4 a0 = *reinterpret_cast<const float4*>(ar + kk * RANK);
      const float4 a1 = *reinterpret_cast<const float4*>(ar + kk * RANK + 4);
      const float4 a2 = *reinterpret_cast<const float4*>(ar + kk * RANK + 8);
      const float4 a3 = *reinterpret_cast<const float4*>(ar + kk * RANK + 12);
      acc[0]  = fmaf(x, a0.x, acc[0]);  acc[1]  = fmaf(x, a0.y, acc[1]);
      acc[2]  = fmaf(x, a0.z, acc[2]);  acc[3]  = fmaf(x, a0.w, acc[3]);
      acc[4]  = fmaf(x, a1.x, acc[4]);  acc[5]  = fmaf(x, a1.y, acc[5]);
      acc[6]  = fmaf(x, a1.z, acc[6]);  acc[7]  = fmaf(x, a1.w, acc[7]);
      acc[8]  = fmaf(x, a2.x, acc[8]);  acc[9]  = fmaf(x, a2.y, acc[9]);
      acc[10] = fmaf(x, a2.z, acc[10]); acc[11] = fmaf(x, a2.w, acc[11]);
      acc[12] = fmaf(x, a3.x, acc[12]); acc[13] = fmaf(x, a3.y, acc[13]);
      acc[14] = fmaf(x, a3.z, acc[14]); acc[15] = fmaf(x, a3.w, acc[15]);
    }
  }

  // ---- park per-(wave,half) partials, then 8-way reduce ----
  float* pp = &part[wv * 2 + h][row32][0];
#pragma unroll
  for (int rq = 0; rq < 4; ++rq)
    *reinterpret_cast<float4*>(pp + rq * 4) =
        make_float4(acc[rq * 4], acc[rq * 4 + 1], acc[rq * 4 + 2], acc[rq * 4 + 3]);
  __syncthreads();

#pragma unroll
  for (int v = tid; v < ROWS_A * RANK; v += 256) {
    const int row = v >> 4;        // 0..31
    const int r   = v & 15;
    float s = 0.f;
#pragma unroll
    for (int p = 0; p < 8; ++p) s += part[p][row][r];
    tmp[((size_t)(b * 2048 + row0 + row)) * RANK + r] = s;
  }
}

// ---------------------------------------------------------------------------
// Kernel 3 (phase B): out[b][row][o] = sum_r tmp[b][row][r] * Bm[b][r][o]
// ROUND-5 FIX: round 4 spilled the 64-VGPR B-slab to scratch
// (VGPR_Count=64, FETCH 272MB, WRITE 248MB = spill round-trips).
//   - __launch_bounds__(256, 2): allow ~128+ VGPRs so B4 stays in registers.
//   - no local tv[] array: FMAs consume the float4 temporaries directly.
// ---------------------------------------------------------------------------
__global__ __launch_bounds__(256, 2) void lora_phase_b(
    const float* __restrict__ tmp,  // [8][2048][16]
    const float* __restrict__ Bm,   // [8][16][2048] (pre-scaled by 2)
    float* __restrict__ out)        // [8][2048][2048]
{
  const int tid  = threadIdx.x;
  const int b    = blockIdx.x >> 6;          // 8 batches
  const int oh   = (blockIdx.x >> 5) & 1;    // column half
  const int rt   = blockIdx.x & 31;          // row tile
  const int row0 = rt * 64;
  const int o0   = oh * 1024 + tid * 4;

  const float* Bb = Bm + (size_t)b * (RANK * 2048) + o0;
  float4 B4[RANK];
#pragma unroll
  for (int r = 0; r < RANK; ++r)
    B4[r] = *reinterpret_cast<const float4*>(Bb + (size_t)r * 2048);

  const float* tp = tmp + ((size_t)(b * 2048 + row0)) * RANK;
  float* op = out + ((size_t)(b * 2048 + row0)) * 2048 + o0;

#pragma unroll 4
  for (int rr = 0; rr < 64; ++rr) {
    const float4 t0 = *reinterpret_cast<const float4*>(tp + rr * RANK);
    const float4 t1 = *reinterpret_cast<const float4*>(tp + rr * RANK + 4);
    const float4 t2 = *reinterpret_cast<const float4*>(tp + rr * RANK + 8);
    const float4 t3 = *reinterpret_cast<const float4*>(tp + rr * RANK + 12);
    float4 a = make_float4(0.f, 0.f, 0.f, 0.f);
    a.x = fmaf(t0.x, B4[0].x, a.x);  a.y = fmaf(t0.x, B4[0].y, a.y);
    a.z = fmaf(t0.x, B4[0].z, a.z);  a.w = fmaf(t0.x, B4[0].w, a.w);
    a.x = fmaf(t0.y, B4[1].x, a.x);  a.y = fmaf(t0.y, B4[1].y, a.y);
    a.z = fmaf(t0.y, B4[1].z, a.z);  a.w = fmaf(t0.y, B4[1].w, a.w);
    a.x = fmaf(t0.z, B4[2].x, a.x);  a.y = fmaf(t0.z, B4[2].y, a.y);
    a.z = fmaf(t0.z, B4[2].z, a.z);  a.w = fmaf(t0.z, B4[2].w, a.w);
    a.x = fmaf(t0.w, B4[3].x, a.x);  a.y = fmaf(t0.w, B4[3].y, a.y);
    a.z = fmaf(t0.w, B4[3].z, a.z);  a.w = fmaf(t0.w, B4[3].w, a.w);
    a.x = fmaf(t1.x, B4[4].x, a.x);  a.y = fmaf(t1.x, B4[4].y, a.y);
    a.z = fmaf(t1.x, B4[4].z, a.z);  a.w = fmaf(t1.x, B4[4].w, a.w);
    a.x = fmaf(t1.y, B4[5].x, a.x);  a.y = fmaf(t1.y, B4[5].y, a.y);
    a.z = fmaf(t1.y, B4[5].z, a.z);  a.w = fmaf(t1.y, B4[5].w, a.w);
    a.x = fmaf(t1.z, B4[6].x, a.x);  a.y = fmaf(t1.z, B4[6].y, a.y);
    a.z = fmaf(t1.z, B4[6].z, a.z);  a.w = fmaf(t1.z, B4[6].w, a.w);
    a.x = fmaf(t1.w, B4[7].x, a.x);  a.y = fmaf(t1.w, B4[7].y, a.y);
    a.z = fmaf(t1.w, B4[7].z, a.z);  a.w = fmaf(t1.w, B4[7].w, a.w);
    a.x = fmaf(t2.x, B4[8].x, a.x);  a.y = fmaf(t2.x, B4[8].y, a.y);
    a.z = fmaf(t2.x, B4[8].z, a.z);  a.w = fmaf(t2.x, B4[8].w, a.w);
    a.x = fmaf(t2.y, B4[9].x, a.x);  a.y = fmaf(t2.y, B4[9].y, a.y);
    a.z = fmaf(t2.y, B4[9].z, a.z);  a.w = fmaf(t2.y, B4[9].w, a.w);
    a.x = fmaf(t2.z, B4[10].x, a.x); a.y = fmaf(t2.z, B4[10].y, a.y);
    a.z = fmaf(t2.z, B4[10].z, a.z); a.w = fmaf(t2.z, B4[10].w, a.w);
    a.x = fmaf(t2.w, B4[11].x, a.x); a.y = fmaf(t2.w, B4[11].y, a.y);
    a.z = fmaf(t2.w, B4[11].z, a.z); a.w = fmaf(t2.w, B4[11].w, a.w);
    a.x = fmaf(t3.x, B4[12].x, a.x); a.y = fmaf(t3.x, B4[12].y, a.y);
    a.z = fmaf(t3.x, B4[12].z, a.z); a.w = fmaf(t3.x, B4[12].w, a.w);
    a.x = fmaf(t3.y, B4[13].x, a.x); a.y = fmaf(t3.y, B4[13].y, a.y);
    a.z = fmaf(t3.y, B4[13].z, a.z); a.w = fmaf(t3.y, B4[13].w, a.w);
    a.x = fmaf(t3.z, B4[14].x, a.x); a.y = fmaf(t3.z, B4[14].y, a.y);
    a.z = fmaf(t3.z, B4[14].z, a.z); a.w = fmaf(t3.z, B4[14].w, a.w);
    a.x = fmaf(t3.w, B4[15].x, a.x); a.y = fmaf(t3.w, B4[15].y, a.y);
    a.z = fmaf(t3.w, B4[15].z, a.z); a.w = fmaf(t3.w, B4[15].w, a.w);
    *reinterpret_cast<float4*>(op + (size_t)rr * 2048) = a;
  }
}

// ---------------------------------------------------------------------------
extern "C" void kernel_launch(void* const* d_in, const int* in_sizes, int n_in,
                              void* d_out, int out_size, void* d_ws, size_t ws_size,
                              hipStream_t stream) {
  const float* input = (const float*)d_in[0];   // [8][2048][2048]
  const float* w     = (const float*)d_in[1];   // [8][4][8]
  const float* la    = (const float*)d_in[2];   // [4][8][512][16]
  const float* lb    = (const float*)d_in[3];   // [4][8][16][512]
  float* outp = (float*)d_out;

  float* At  = (float*)d_ws;                    // 262144 floats (1 MB)
  float* Bm  = At + 8 * RANK * 2048;            // 262144 floats (1 MB)
  float* tmp = Bm + 8 * RANK * 2048;            // 262144 floats (1 MB)

  skilled_lora_mix<<<512, 256, 0, stream>>>(w, la, lb, At, Bm);
  lora_phase_a<<<512, 256, 0, stream>>>(input, At, tmp);
  lora_phase_b<<<512, 256, 0, stream>>>(tmp, Bm, outp);
}